// Round 3
// baseline (79.569 us; speedup 1.0000x reference)
//
#include <hip/hip_runtime.h>

#define MAXT 100000.0f

constexpr int B    = 64;
constexpr int IN   = 1024;
constexpr int N    = 1025;   // IN + bias column
constexpr int OUTS = 512;
constexpr int NSEG = 16;     // segment-waves per block (1024 threads)
constexpr int SEGL = 64;     // uniform segment length; i=1024 is sub-31 tail
constexpr unsigned KEYMASK = 0xFFFFFC00u;  // top 22 value bits | 10-bit index
constexpr unsigned BIASKEY = 0x3F8003FFu;  // key upper bound for bias rank

struct alignas(8) Pair { unsigned off; unsigned x; };
struct alignas(16) Pair2 { Pair a, b; };

// ---------------- Fused: per-row sort + gathered-weight scan ----------------
// grid = (B, 4) = 256 blocks -> one block-round on 256 CUs.
// R9 changes vs R8 (78.15 us total, kernel ~16.5 us; scan is at the L2-BW
// floor ~7.5 us, so this round attacks latency/barrier slack):
//  * sort: fused LDS stage-pairs (jj, jj/2) -> 6 barriers (was 10)
//  * pass 2: 32 sub-segments of 32 rows, half-wave each, float4 (4 col/thr)
//    -> serial depth halved, VMEM instr halved; software-pipelined prefetch
//  * pass 1: emits sub-segment sums via uu=16 snapshot (even/odd row split
//    makes the combined snapshot exactly rows 0..31); seg-15 stops at 32 rows
//  * first pass-2 Pair+weight loads hoisted before the barrier (T14-lite)
__global__ __launch_bounds__(1024, 4) void snn_fused(
    const float* __restrict__ layer_in,
    const float* __restrict__ weight,
    const float* __restrict__ delay,
    float* __restrict__ out) {
  __shared__ unsigned ksh[2][IN];            // double-buffered sort exchange
  __shared__ float vsh[IN];
  __shared__ __align__(16) Pair ps[N + 1];
  __shared__ float4 redT[NSEG][64];          // full-segment sums (col-pair layout)
  __shared__ float4 redA[NSEG][64];          // first-half (rows 0..31) sums
  __shared__ __align__(16) int redm[128];    // final min (int bits of nonneg f32)

  const int b    = blockIdx.x;
  const int jc   = blockIdx.y;
  const int lane = threadIdx.x;
  const int seg  = threadIdx.y;
  const int tid  = seg * 64 + lane;
  const int half = lane >> 5;
  const int q    = lane & 31;          // col-quad index (cols 4q..4q+3)
  const unsigned jadd4 = (unsigned)((jc * 128 + q * 4) * 4);  // byte offset

  if (tid < 128) redm[tid] = __float_as_int(MAXT);  // fenced by sort barriers

  // ---- Phase A: scaled input + 1-elem/thread bitonic argsort ----
  {
    float d = delay[tid];
    float v = layer_in[b * IN + tid] * expf(d > 0.0f ? d : 0.0f);
    vsh[tid] = v;                                 // exact x, gathered at end
    unsigned k = (__float_as_uint(v) & KEYMASK) | (unsigned)tid;

    auto sop = [](unsigned x, unsigned y, bool tmin) {
      unsigned mn = x < y ? x : y;
      unsigned mx = x < y ? y : x;
      return tmin ? mn : mx;
    };
    int pb = 0;  // constant-folded (straight-line calls)
    // Single cross-wave stage. Double-buffer: one barrier per round is safe —
    // a thread can only reach round t+2's write after passing round t+1's
    // barrier, which requires ALL threads past round t's reads.
    auto lds1 = [&](unsigned kv, int KK, int JJ) {
      ksh[pb][tid] = kv; __syncthreads();
      unsigned o = ksh[pb][tid ^ JJ];
      pb ^= 1;
      return sop(kv, o, ((tid & KK) == 0) == ((tid & JJ) == 0));
    };
    // Fused pair of cross-wave stages (JJ then JJ/2) in ONE round-trip.
    // Partner p = tid^J2 has identical up/lower flags for stage JJ (J2 is a
    // different bit), so its stage-JJ result is computable locally from
    // ksh[p] and ksh[p^JJ].
    auto lds2 = [&](unsigned kv, int KK, int JJ) {
      int J2 = JJ >> 1;
      ksh[pb][tid] = kv; __syncthreads();
      unsigned o = ksh[pb][tid ^ JJ];
      unsigned a = ksh[pb][tid ^ J2];
      unsigned c = ksh[pb][tid ^ (JJ | J2)];
      pb ^= 1;
      bool up = ((tid & KK) == 0);
      bool s1 = up == ((tid & JJ) == 0);
      unsigned k1  = sop(kv, o, s1);    // own stage-JJ result
      unsigned k1p = sop(a, c, s1);     // partner's stage-JJ result
      return sop(k1, k1p, up == ((tid & J2) == 0));
    };
    auto tailw = [&](unsigned kv, int KK) {   // in-wave stages jj = 32..1
#pragma unroll
      for (int jj = 32; jj > 0; jj >>= 1) {
        unsigned o = __shfl_xor(kv, jj, 64);
        kv = sop(kv, o, ((tid & KK) == 0) == ((tid & jj) == 0));
      }
      return kv;
    };

#pragma unroll
    for (int kk = 2; kk <= 64; kk <<= 1)
#pragma unroll
      for (int jj = kk >> 1; jj > 0; jj >>= 1) {
        unsigned o = __shfl_xor(k, jj, 64);
        k = sop(k, o, ((tid & kk) == 0) == ((tid & jj) == 0));
      }

    k = lds1(k, 128, 64);                           k = tailw(k, 128);
    k = lds2(k, 256, 128);                          k = tailw(k, 256);
    k = lds2(k, 512, 256);   k = lds1(k, 512, 64);  k = tailw(k, 512);
    k = lds2(k, 1024, 512);  k = lds2(k, 1024, 128); k = tailw(k, 1024);

    // bias (x=1.0, idx=IN) rank = #elements sorting before it (stable order)
    int r = __syncthreads_count((k <= BIASKEY) ? 1 : 0);

    int idx = (int)(k & 1023u);
    float x = vsh[idx];
    int pos = tid + (tid >= r);
    Pair pr; pr.off = (unsigned)(idx * OUTS * 4); pr.x = __float_as_uint(x);
    ps[pos] = pr;
    if (tid == 0) {
      Pair bias; bias.off = (unsigned)(IN * OUTS * 4); bias.x = __float_as_uint(1.0f);
      ps[r] = bias;
      Pair sent; sent.off = 0u; sent.x = __float_as_uint(MAXT);
      ps[N] = sent;
    }
    __syncthreads();
  }

  // ---- Phase B ----
  const char* wbase = (const char*)weight;
  const int is = seg * SEGL;

  // Pass 1: float4 loads, halves take even/odd rows, shfl_xor(32) combine.
  // Snapshot at uu=16 == exact sum of rows 0..31 (sub-segment A).
  {
    float4 sw = make_float4(0.f, 0.f, 0.f, 0.f);
    float4 sx = make_float4(0.f, 0.f, 0.f, 0.f);
#pragma unroll 8
    for (int uu = 0; uu < 16; ++uu) {
      Pair p = ps[is + 2 * uu + half];
      float4 w = *(const float4*)(wbase + (p.off + jadd4));
      float xv = __uint_as_float(p.x);
      sw.x += w.x; sw.y += w.y; sw.z += w.z; sw.w += w.w;
      sx.x = fmaf(w.x, xv, sx.x);
      sx.y = fmaf(w.y, xv, sx.y);
      sx.z = fmaf(w.z, xv, sx.z);
      sx.w = fmaf(w.w, xv, sx.w);
    }
    sw.x += __shfl_xor(sw.x, 32, 64);  sw.y += __shfl_xor(sw.y, 32, 64);
    sw.z += __shfl_xor(sw.z, 32, 64);  sw.w += __shfl_xor(sw.w, 32, 64);
    sx.x += __shfl_xor(sx.x, 32, 64);  sx.y += __shfl_xor(sx.y, 32, 64);
    sx.z += __shfl_xor(sx.z, 32, 64);  sx.w += __shfl_xor(sx.w, 32, 64);
    if (half == 0) {
      redA[seg][2 * q]     = make_float4(sw.x, sw.y, sx.x, sx.y);
      redA[seg][2 * q + 1] = make_float4(sw.z, sw.w, sx.z, sx.w);
    }
    if (seg < NSEG - 1) {              // seg-15's T feeds no prefix: skip
      float4 tw = sw, tx = sx;         // combined sub-A (both halves hold it)
      sw = make_float4(0.f, 0.f, 0.f, 0.f);
      sx = make_float4(0.f, 0.f, 0.f, 0.f);
#pragma unroll 8
      for (int uu = 16; uu < 32; ++uu) {
        Pair p = ps[is + 2 * uu + half];
        float4 w = *(const float4*)(wbase + (p.off + jadd4));
        float xv = __uint_as_float(p.x);
        sw.x += w.x; sw.y += w.y; sw.z += w.z; sw.w += w.w;
        sx.x = fmaf(w.x, xv, sx.x);
        sx.y = fmaf(w.y, xv, sx.y);
        sx.z = fmaf(w.z, xv, sx.z);
        sx.w = fmaf(w.w, xv, sx.w);
      }
      sw.x += __shfl_xor(sw.x, 32, 64);  sw.y += __shfl_xor(sw.y, 32, 64);
      sw.z += __shfl_xor(sw.z, 32, 64);  sw.w += __shfl_xor(sw.w, 32, 64);
      sx.x += __shfl_xor(sx.x, 32, 64);  sx.y += __shfl_xor(sx.y, 32, 64);
      sx.z += __shfl_xor(sx.z, 32, 64);  sx.w += __shfl_xor(sx.w, 32, 64);
      tw.x += sw.x; tw.y += sw.y; tw.z += sw.z; tw.w += sw.w;
      tx.x += sx.x; tx.y += sx.y; tx.z += sx.z; tx.w += sx.w;
      if (half == 0) {
        redT[seg][2 * q]     = make_float4(tw.x, tw.y, tx.x, tx.y);
        redT[seg][2 * q + 1] = make_float4(tw.z, tw.w, tx.z, tx.w);
      }
    }
  }

  // T14-lite: issue pass-2's first Pair + weight row before the barrier
  // (addresses depend only on ps); the barrier's vmcnt drain hides them.
  const int isub = (seg * 2 + half) * 32;
  Pair2 t0 = *(const Pair2*)(ps + isub);
  float4 w0 = *(const float4*)(wbase + (t0.a.off + jadd4));
  __syncthreads();

  // Prefix: base = -1 + sum of full-segment totals below; half-1 adds its
  // sibling sub-A. Both halves read the SAME redT addresses -> LDS broadcast.
  float wc0 = -1.f, wc1 = -1.f, wc2 = -1.f, wc3 = -1.f;
  float wi0 = 0.f,  wi1 = 0.f,  wi2 = 0.f,  wi3 = 0.f;
  for (int s = 0; s < seg; ++s) {
    float4 a = redT[s][2 * q], c = redT[s][2 * q + 1];
    wc0 += a.x; wc1 += a.y; wi0 += a.z; wi1 += a.w;
    wc2 += c.x; wc3 += c.y; wi2 += c.z; wi3 += c.w;
  }
  if (half) {
    float4 a = redA[seg][2 * q], c = redA[seg][2 * q + 1];
    wc0 += a.x; wc1 += a.y; wi0 += a.z; wi1 += a.w;
    wc2 += c.x; wc3 += c.y; wi2 += c.z; wi3 += c.w;
  }

  // Pass 2: latch first valid per col (bd<0 == "not found").
  // valid(u) <=> min(wc, -h_prev, h, -bd) >= 0, h = x_{u+1}*wc - wi.
  float bn0 = MAXT, bn1 = MAXT, bn2 = MAXT, bn3 = MAXT;
  float bd0 = -1.f, bd1 = -1.f, bd2 = -1.f, bd3 = -1.f;
  Pair pcur = t0.a, pnx = t0.b;
  float4 wcur = w0;
  float hp0, hp1, hp2, hp3;
  {
    float x0 = __uint_as_float(pcur.x);
    hp0 = fmaf(x0, wc0, -wi0);
    hp1 = fmaf(x0, wc1, -wi1);
    hp2 = fmaf(x0, wc2, -wi2);
    hp3 = fmaf(x0, wc3, -wi3);
  }

#define STEP(W, XI, XN)                                                  \
  {                                                                      \
    wc0 += (W).x; wi0 = fmaf((W).x, (XI), wi0);                          \
    wc1 += (W).y; wi1 = fmaf((W).y, (XI), wi1);                          \
    wc2 += (W).z; wi2 = fmaf((W).z, (XI), wi2);                          \
    wc3 += (W).w; wi3 = fmaf((W).w, (XI), wi3);                          \
    float h0 = fmaf((XN), wc0, -wi0), h1 = fmaf((XN), wc1, -wi1);        \
    float h2 = fmaf((XN), wc2, -wi2), h3 = fmaf((XN), wc3, -wi3);        \
    float q0 = fminf(fminf(wc0, -hp0), fminf(h0, -bd0));                 \
    float q1 = fminf(fminf(wc1, -hp1), fminf(h1, -bd1));                 \
    float q2 = fminf(fminf(wc2, -hp2), fminf(h2, -bd2));                 \
    float q3 = fminf(fminf(wc3, -hp3), fminf(h3, -bd3));                 \
    bool f0 = q0 >= 0.f, f1 = q1 >= 0.f, f2 = q2 >= 0.f, f3 = q3 >= 0.f; \
    bn0 = f0 ? wi0 : bn0;  bd0 = f0 ? wc0 : bd0;                         \
    bn1 = f1 ? wi1 : bn1;  bd1 = f1 ? wc1 : bd1;                         \
    bn2 = f2 ? wi2 : bn2;  bd2 = f2 ? wc2 : bd2;                         \
    bn3 = f3 ? wi3 : bn3;  bd3 = f3 ? wc3 : bd3;                         \
    hp0 = h0; hp1 = h1; hp2 = h2; hp3 = h3;                              \
  }

#pragma unroll 4
  for (int u = 0; u < 31; ++u) {
    Pair pnn = ps[isub + u + 2];           // uniform per half-wave: broadcast
    float4 wn = *(const float4*)(wbase + (pnx.off + jadd4));
    float xc = __uint_as_float(pcur.x);
    float xn = __uint_as_float(pnx.x);
    STEP(wcur, xc, xn);
    pcur = pnx; pnx = pnn; wcur = wn;
  }
  {  // row 31 of the sub-segment (no further prefetch)
    float xc = __uint_as_float(pcur.x);
    float xn = __uint_as_float(pnx.x);
    STEP(wcur, xc, xn);
  }
  if (seg == NSEG - 1 && half == 1) {      // global tail element rank 1024
    Pair pt = pnx;                          // ps[1024]
    Pair se = ps[N];                        // MAXT sentinel
    float4 wt = *(const float4*)(wbase + (pt.off + jadd4));
    float xc = __uint_as_float(pt.x);
    float xn = __uint_as_float(se.x);
    STEP(wt, xc, xn);
  }
#undef STEP

  float s0 = (bd0 < 0.f) ? MAXT : bn0 * __builtin_amdgcn_rcpf(fmaxf(bd0, 1e-10f));
  float s1 = (bd1 < 0.f) ? MAXT : bn1 * __builtin_amdgcn_rcpf(fmaxf(bd1, 1e-10f));
  float s2 = (bd2 < 0.f) ? MAXT : bn2 * __builtin_amdgcn_rcpf(fmaxf(bd2, 1e-10f));
  float s3 = (bd3 < 0.f) ? MAXT : bn3 * __builtin_amdgcn_rcpf(fmaxf(bd3, 1e-10f));

  // Candidates are nonneg floats <= MAXT -> int-bit atomicMin == float min.
  atomicMin(&redm[q * 4 + 0], __float_as_int(s0));
  atomicMin(&redm[q * 4 + 1], __float_as_int(s1));
  atomicMin(&redm[q * 4 + 2], __float_as_int(s2));
  atomicMin(&redm[q * 4 + 3], __float_as_int(s3));
  __syncthreads();
  if (tid < 32) {
    int4 mv = *(const int4*)(&redm[tid * 4]);
    float4 o = make_float4(__int_as_float(mv.x), __int_as_float(mv.y),
                           __int_as_float(mv.z), __int_as_float(mv.w));
    *(float4*)(&out[b * OUTS + jc * 128 + tid * 4]) = o;
  }
}

extern "C" void kernel_launch(void* const* d_in, const int* in_sizes, int n_in,
                              void* d_out, int out_size, void* d_ws, size_t ws_size,
                              hipStream_t stream) {
  const float* layer_in = (const float*)d_in[0];
  const float* weight   = (const float*)d_in[1];
  const float* delay    = (const float*)d_in[2];
  float* out = (float*)d_out;
  (void)d_ws; (void)ws_size;

  snn_fused<<<dim3(B, OUTS / 128), dim3(64, NSEG), 0, stream>>>(
      layer_in, weight, delay, out);
}

// Round 4
// 78.336 us; speedup vs baseline: 1.0157x; 1.0157x over previous
//
#include <hip/hip_runtime.h>

#define MAXT 100000.0f

constexpr int B    = 64;
constexpr int IN   = 1024;
constexpr int N    = 1025;   // IN + bias column
constexpr int OUTS = 512;
constexpr int NSEG = 16;     // segment-waves per block (1024 threads)
constexpr int SEGL = 64;     // uniform segment length; i=1024 is seg-15 tail
constexpr unsigned KEYMASK = 0xFFFFFC00u;  // top 22 value bits | 10-bit index
constexpr unsigned BIASKEY = 0x3F8003FFu;  // key upper bound for bias rank

struct alignas(8) Pair { unsigned off; unsigned x; };
struct alignas(16) Pair2 { Pair a, b; };   // one ds_read_b128

// ---------------- Fused: per-row sort + gathered-weight scan, 2 j/thread ----
// grid = (B, 4) = 256 blocks -> one block-round on 256 CUs.
// R10 = R8 structure (best measured, 78.15 us) + fused sort stage-pairs ONLY.
// R9's pass-2 4-col restructure regressed (+1.4 us; register pressure under
// the 128-VGPR launch-bounds cap) and is reverted wholesale.
//  * sort: fused LDS stage-pairs (jj, jj/2) -> 6 barriers (was 10)
//  * pass 1: float4 loads, even/odd row split, shfl_xor(32) combine (R8)
//  * pass 2: 2 j/thread, h-recurrence, Pair2 ds_read_b128, unroll-2 (R8)
//  * final reduce: LDS atomicMin on int bits of nonneg floats (R8)
__global__ __launch_bounds__(1024, 4) void snn_fused(
    const float* __restrict__ layer_in,
    const float* __restrict__ weight,
    const float* __restrict__ delay,
    float* __restrict__ out) {
  __shared__ unsigned ksh[2][IN];            // double-buffered sort exchange
  __shared__ float vsh[IN];
  __shared__ __align__(16) Pair ps[N + 1];
  __shared__ float4 red4[NSEG][64];          // pass-1 partials
  __shared__ int redm[128];                  // final min (int bits of nonneg f32)

  const int b    = blockIdx.x;
  const int jc   = blockIdx.y;
  const int lane = threadIdx.x;        // j pair
  const int seg  = threadIdx.y;        // i segment
  const int tid  = seg * 64 + lane;
  const unsigned jadd = (unsigned)((jc * 128 + lane * 2) * 4);  // byte offset

  if (tid < 128) redm[tid] = __float_as_int(MAXT);  // fenced by sort barriers

  // ---- Phase A: scaled input + 1-elem/thread bitonic argsort ----
  {
    float d = delay[tid];
    float v = layer_in[b * IN + tid] * expf(d > 0.0f ? d : 0.0f);
    vsh[tid] = v;                                 // exact x, gathered at end
    unsigned k = (__float_as_uint(v) & KEYMASK) | (unsigned)tid;

    auto sop = [](unsigned x, unsigned y, bool tmin) {
      unsigned mn = x < y ? x : y;
      unsigned mx = x < y ? y : x;
      return tmin ? mn : mx;
    };
    int pb = 0;  // constant-folded (straight-line calls)
    // Single cross-wave stage. Double-buffer: one barrier per round is safe —
    // a thread reaches round t+2's write only after round t+1's barrier,
    // which requires ALL threads past round t's reads.
    auto lds1 = [&](unsigned kv, int KK, int JJ) {
      ksh[pb][tid] = kv; __syncthreads();
      unsigned o = ksh[pb][tid ^ JJ];
      pb ^= 1;
      return sop(kv, o, ((tid & KK) == 0) == ((tid & JJ) == 0));
    };
    // Fused pair of cross-wave stages (JJ then JJ/2) in ONE round-trip.
    // Partner p = tid^J2 has identical up/lower flags for stage JJ (J2 is a
    // different bit), so its stage-JJ result is computable locally from
    // ksh[p] and ksh[p^JJ]. Validated on HW in R9 (passed).
    auto lds2 = [&](unsigned kv, int KK, int JJ) {
      int J2 = JJ >> 1;
      ksh[pb][tid] = kv; __syncthreads();
      unsigned o = ksh[pb][tid ^ JJ];
      unsigned a = ksh[pb][tid ^ J2];
      unsigned c = ksh[pb][tid ^ (JJ | J2)];
      pb ^= 1;
      bool up = ((tid & KK) == 0);
      bool s1 = up == ((tid & JJ) == 0);
      unsigned k1  = sop(kv, o, s1);    // own stage-JJ result
      unsigned k1p = sop(a, c, s1);     // partner's stage-JJ result
      return sop(k1, k1p, up == ((tid & J2) == 0));
    };
    auto tailw = [&](unsigned kv, int KK) {   // in-wave stages jj = 32..1
#pragma unroll
      for (int jj = 32; jj > 0; jj >>= 1) {
        unsigned o = __shfl_xor(kv, jj, 64);
        kv = sop(kv, o, ((tid & KK) == 0) == ((tid & jj) == 0));
      }
      return kv;
    };

#pragma unroll
    for (int kk = 2; kk <= 64; kk <<= 1)
#pragma unroll
      for (int jj = kk >> 1; jj > 0; jj >>= 1) {
        unsigned o = __shfl_xor(k, jj, 64);
        k = sop(k, o, ((tid & kk) == 0) == ((tid & jj) == 0));
      }

    k = lds1(k, 128, 64);                            k = tailw(k, 128);
    k = lds2(k, 256, 128);                           k = tailw(k, 256);
    k = lds2(k, 512, 256);   k = lds1(k, 512, 64);   k = tailw(k, 512);
    k = lds2(k, 1024, 512);  k = lds2(k, 1024, 128); k = tailw(k, 1024);

    // bias (x=1.0, idx=IN) rank = #elements sorting before it (stable order)
    int r = __syncthreads_count((k <= BIASKEY) ? 1 : 0);

    int idx = (int)(k & 1023u);
    float x = vsh[idx];
    int pos = tid + (tid >= r);
    Pair pr; pr.off = (unsigned)(idx * OUTS * 4); pr.x = __float_as_uint(x);
    ps[pos] = pr;
    if (tid == 0) {
      Pair bias; bias.off = (unsigned)(IN * OUTS * 4); bias.x = __float_as_uint(1.0f);
      ps[r] = bias;
      Pair sent; sent.off = 0u; sent.x = __float_as_uint(MAXT);
      ps[N] = sent;
    }
    __syncthreads();
  }

  // ---- Phase B: segmented scan, first-valid latch, 2 j per thread ----
  const char* wbase = (const char*)weight;
  const int is = seg * SEGL;

  // Pass 1: per-segment partial sums of (w, w*x) via float4, rows split
  // across lane halves (half h takes rows 2*uu+h), combined with shfl_xor(32).
  // Seg 15's total feeds no exclusive prefix -> skip (wave-uniform branch).
  if (seg < NSEG - 1) {
    const int half = lane >> 5;
    const int q    = lane & 31;                       // j-quad index
    const unsigned jadd4 = (unsigned)((jc * 128 + q * 4) * 4);
    float4 sw = make_float4(0.f, 0.f, 0.f, 0.f);
    float4 sx = make_float4(0.f, 0.f, 0.f, 0.f);
#pragma unroll 8
    for (int uu = 0; uu < SEGL / 2; ++uu) {
      Pair p = ps[is + 2 * uu + half];
      float4 w = *(const float4*)(wbase + (p.off + jadd4));
      float xv = __uint_as_float(p.x);
      sw.x += w.x; sw.y += w.y; sw.z += w.z; sw.w += w.w;
      sx.x = fmaf(w.x, xv, sx.x);
      sx.y = fmaf(w.y, xv, sx.y);
      sx.z = fmaf(w.z, xv, sx.z);
      sx.w = fmaf(w.w, xv, sx.w);
    }
    sw.x += __shfl_xor(sw.x, 32, 64);
    sw.y += __shfl_xor(sw.y, 32, 64);
    sw.z += __shfl_xor(sw.z, 32, 64);
    sw.w += __shfl_xor(sw.w, 32, 64);
    sx.x += __shfl_xor(sx.x, 32, 64);
    sx.y += __shfl_xor(sx.y, 32, 64);
    sx.z += __shfl_xor(sx.z, 32, 64);
    sx.w += __shfl_xor(sx.w, 32, 64);
    if (half == 0) {                 // same layout pass 2 expects: per j-pair
      red4[seg][2 * q]     = make_float4(sw.x, sw.y, sx.x, sx.y);
      red4[seg][2 * q + 1] = make_float4(sw.z, sw.w, sx.z, sx.w);
    }
  }
  __syncthreads();

  // Exclusive prefix over segments; wc holds w_cum - 1.
  float wc0 = -1.0f, wc1 = -1.0f, wi0 = 0.0f, wi1 = 0.0f;
  for (int s = 0; s < seg; ++s) {
    float4 t = red4[s][lane];
    wc0 += t.x; wc1 += t.y; wi0 += t.z; wi1 += t.w;
  }

  // Pass 2: latch first valid candidate per j (bd<0 encodes "not found").
  // valid(u) <=> min3(wc_u, -h_{u-1}, h_u) >= 0 with h_u = x_{u+1}*wc_u - wi_u
  // (identity: g_{u+1} = wi - x*wc quantity == -h_u exactly). xs sorted =>
  // first valid IS the filtered min. Latch test folded: min(m, -bd) >= 0.
  float bn0 = MAXT, bd0 = -1.0f, bn1 = MAXT, bd1 = -1.0f;
  Pair pa, pbp;
  { Pair2 t = *(const Pair2*)(ps + is); pa = t.a; pbp = t.b; }
  float hp0, hp1;
  {
    float x0 = __uint_as_float(pa.x);
    hp0 = fmaf(x0, wc0, -wi0);     // -g at segment start
    hp1 = fmaf(x0, wc1, -wi1);
  }
#pragma unroll 4
  for (int u = 0; u < SEGL; u += 2) {
    Pair2 nx = *(const Pair2*)(ps + is + u + 2);   // ds_read_b128, 16-aligned
    {
      float2 w = *(const float2*)(wbase + (pa.off + jadd));
      float xi = __uint_as_float(pa.x);
      float xn = __uint_as_float(pbp.x);
      wc0 += w.x; wi0 = fmaf(w.x, xi, wi0);
      wc1 += w.y; wi1 = fmaf(w.y, xi, wi1);
      float h0 = fmaf(xn, wc0, -wi0);
      float h1 = fmaf(xn, wc1, -wi1);
      float q0 = fminf(fminf(fminf(wc0, -hp0), h0), -bd0);
      float q1 = fminf(fminf(fminf(wc1, -hp1), h1), -bd1);
      bool f0 = q0 >= 0.0f;
      bool f1 = q1 >= 0.0f;
      bn0 = f0 ? wi0 : bn0;  bd0 = f0 ? wc0 : bd0;
      bn1 = f1 ? wi1 : bn1;  bd1 = f1 ? wc1 : bd1;
      hp0 = h0; hp1 = h1;
    }
    {
      float2 w = *(const float2*)(wbase + (pbp.off + jadd));
      float xi = __uint_as_float(pbp.x);
      float xn = __uint_as_float(nx.a.x);
      wc0 += w.x; wi0 = fmaf(w.x, xi, wi0);
      wc1 += w.y; wi1 = fmaf(w.y, xi, wi1);
      float h0 = fmaf(xn, wc0, -wi0);
      float h1 = fmaf(xn, wc1, -wi1);
      float q0 = fminf(fminf(fminf(wc0, -hp0), h0), -bd0);
      float q1 = fminf(fminf(fminf(wc1, -hp1), h1), -bd1);
      bool f0 = q0 >= 0.0f;
      bool f1 = q1 >= 0.0f;
      bn0 = f0 ? wi0 : bn0;  bd0 = f0 ? wc0 : bd0;
      bn1 = f1 ? wi1 : bn1;  bd1 = f1 ? wc1 : bd1;
      hp0 = h0; hp1 = h1;
    }
    pa = nx.a; pbp = nx.b;
  }
  if (seg == NSEG - 1) {                     // tail element i = 1024
    // loop exit carries pa = ps[1024], pbp = ps[1025] (MAXT sentinel)
    float2 w = *(const float2*)(wbase + (pa.off + jadd));
    float xi = __uint_as_float(pa.x);
    float xn = __uint_as_float(pbp.x);
    wc0 += w.x; wi0 = fmaf(w.x, xi, wi0);
    wc1 += w.y; wi1 = fmaf(w.y, xi, wi1);
    float h0 = fmaf(xn, wc0, -wi0);
    float h1 = fmaf(xn, wc1, -wi1);
    float q0 = fminf(fminf(fminf(wc0, -hp0), h0), -bd0);
    float q1 = fminf(fminf(fminf(wc1, -hp1), h1), -bd1);
    bool f0 = q0 >= 0.0f;
    bool f1 = q1 >= 0.0f;
    bn0 = f0 ? wi0 : bn0;  bd0 = f0 ? wc0 : bd0;
    bn1 = f1 ? wi1 : bn1;  bd1 = f1 ? wc1 : bd1;
  }
  float best0 = (bd0 < 0.0f) ? MAXT : bn0 * __builtin_amdgcn_rcpf(fmaxf(bd0, 1e-10f));
  float best1 = (bd1 < 0.0f) ? MAXT : bn1 * __builtin_amdgcn_rcpf(fmaxf(bd1, 1e-10f));

  // Final reduce: all candidates are nonneg floats (<= MAXT), so int-bit
  // atomicMin == float min. No extra barrier round, no serial 16-iter loop.
  atomicMin(&redm[lane * 2],     __float_as_int(best0));
  atomicMin(&redm[lane * 2 + 1], __float_as_int(best1));
  __syncthreads();
  if (seg == 0) {
    float2 o = make_float2(__int_as_float(redm[lane * 2]),
                           __int_as_float(redm[lane * 2 + 1]));
    *(float2*)(&out[b * OUTS + jc * 128 + lane * 2]) = o;
  }
}

extern "C" void kernel_launch(void* const* d_in, const int* in_sizes, int n_in,
                              void* d_out, int out_size, void* d_ws, size_t ws_size,
                              hipStream_t stream) {
  const float* layer_in = (const float*)d_in[0];
  const float* weight   = (const float*)d_in[1];
  const float* delay    = (const float*)d_in[2];
  float* out = (float*)d_out;
  (void)d_ws; (void)ws_size;

  snn_fused<<<dim3(B, OUTS / 128), dim3(64, NSEG), 0, stream>>>(
      layer_in, weight, delay, out);
}

// Round 5
// 76.249 us; speedup vs baseline: 1.0435x; 1.0274x over previous
//
#include <hip/hip_runtime.h>

#define MAXT 100000.0f

constexpr int B    = 64;
constexpr int IN   = 1024;
constexpr int N    = 1025;   // IN + bias column
constexpr int OUTS = 512;
constexpr int NSEG = 8;      // segment-waves per block (512 threads)
constexpr int SEGL = 128;    // rows per segment; rank 1024 is seg-7 tail
constexpr int JCH  = 64;     // j columns per block
constexpr unsigned KEYMASK = 0xFFFFFC00u;  // top 22 value bits | 10-bit index
constexpr unsigned BIASKEY = 0x3F8003FFu;  // key upper bound for bias rank

struct alignas(8) Pair { unsigned off; unsigned x; };
struct alignas(16) Pair2 { Pair a, b; };   // one ds_read_b128

// ---------------- Fused: per-row sort + gathered-weight scan ----------------
// R11: 512-thread blocks, grid (64,8) = 512 blocks -> 2 blocks/CU.
// Mechanism: R8/R10's 1024-thread single block barrier-locks all 16 waves, so
// memory phases (pass1/2) and VALU phases (sort, latch) serialize -> kernel ==
// sum of per-phase floors (~16.7 us). Two independent 8-wave blocks per CU
// never share a barrier -> phases of different blocks overlap.
//  * sort: 2 elems/thread (v, v^64): jj=64 thread-local, 4 LDS rounds total
//  * pass 1: segs 0..6 of 128 rows, float4 x 4 row-slices, shfl_xor(16,32)
//  * pass 2: 1 col/thread (light regs), R8 h-recurrence, Pair2 reads,
//    2-deep weight-load pipeline
//  * reduce: LDS atomicMin (int bits of nonneg floats)
__global__ __launch_bounds__(512, 4) void snn_fused(
    const float* __restrict__ layer_in,
    const float* __restrict__ weight,
    const float* __restrict__ delay,
    float* __restrict__ out) {
  __shared__ unsigned ksh[2][IN];            // double-buffered sort exchange
  __shared__ float vsh[IN];
  __shared__ __align__(16) Pair ps[N + 1];
  __shared__ float2 red2[NSEG][JCH];         // per-seg (sum w, sum w*x) per col
  __shared__ __align__(16) int redm[JCH];    // final min (int bits)

  const int b    = blockIdx.x;
  const int jc   = blockIdx.y;         // 0..7, 64 cols each
  const int lane = threadIdx.x;        // 0..63 = col
  const int seg  = threadIdx.y;        // 0..7 (wave id)
  const int tid  = seg * 64 + lane;
  const unsigned jadd = (unsigned)((jc * JCH + lane) * 4);   // byte offset

  if (tid < JCH) redm[tid] = __float_as_int(MAXT);  // fenced by sort barriers

  // ---- Phase A: scaled input + 2-elem/thread bitonic argsort ----
  // Thread (lane, seg) owns virtual positions v0 = seg*128+lane (bit6=0) and
  // v1 = v0+64 (bit6=1). Stage (kk,jj) compare-exchange v <-> v^jj, keep-min
  // iff ((v&kk)==0)==((v&jj)==0):  jj<=32 -> shfl (partner same wave);
  // jj==64 -> between k0,k1 of the SAME thread; jj>=128 -> LDS.
  {
    const int v0 = seg * 128 + lane;
    const int v1 = v0 + 64;
    float d0 = delay[v0], d1 = delay[v1];
    float x0 = layer_in[b * IN + v0] * expf(d0 > 0.0f ? d0 : 0.0f);
    float x1 = layer_in[b * IN + v1] * expf(d1 > 0.0f ? d1 : 0.0f);
    vsh[v0] = x0; vsh[v1] = x1;
    unsigned k0 = (__float_as_uint(x0) & KEYMASK) | (unsigned)v0;
    unsigned k1 = (__float_as_uint(x1) & KEYMASK) | (unsigned)v1;

    auto sop = [](unsigned x, unsigned y, bool tmin) {
      unsigned mn = x < y ? x : y;
      unsigned mx = x < y ? y : x;
      return tmin ? mn : mx;
    };
    int pb = 0;
    auto shflst = [&](int KK, int JJ) {     // JJ <= 32
      unsigned o0 = __shfl_xor(k0, JJ, 64);
      unsigned o1 = __shfl_xor(k1, JJ, 64);
      k0 = sop(k0, o0, ((v0 & KK) == 0) == ((v0 & JJ) == 0));
      k1 = sop(k1, o1, ((v1 & KK) == 0) == ((v1 & JJ) == 0));
    };
    auto local64 = [&](int KK) {            // jj == 64: partner is in-thread
      bool up = ((v0 & KK) == 0);           // KK>=128 -> same flag for v1
      unsigned mn = k0 < k1 ? k0 : k1;
      unsigned mx = k0 < k1 ? k1 : k0;
      k0 = up ? mn : mx;
      k1 = up ? mx : mn;
    };
    // One barrier per LDS round is safe (double buffer): a thread reaches
    // round t+2's write only after round t+1's barrier, which requires all
    // threads past round t's reads.
    auto lds1 = [&](int KK, int JJ) {
      ksh[pb][v0] = k0; ksh[pb][v1] = k1;
      __syncthreads();
      unsigned o0 = ksh[pb][v0 ^ JJ];
      unsigned o1 = ksh[pb][v1 ^ JJ];
      pb ^= 1;
      k0 = sop(k0, o0, ((v0 & KK) == 0) == ((v0 & JJ) == 0));
      k1 = sop(k1, o1, ((v1 & KK) == 0) == ((v1 & JJ) == 0));
    };
    // Fused stage-pair (JJ, JJ/2) in one round-trip (validated R9/R10):
    // partner v^J2 shares stage-JJ flags, so its stage-JJ result is
    // computable from ksh[v^J2] and ksh[v^(JJ|J2)].
    auto lds2 = [&](int KK, int JJ) {
      int J2 = JJ >> 1;
      ksh[pb][v0] = k0; ksh[pb][v1] = k1;
      __syncthreads();
      {
        unsigned o = ksh[pb][v0 ^ JJ];
        unsigned a = ksh[pb][v0 ^ J2];
        unsigned c = ksh[pb][v0 ^ (JJ | J2)];
        bool up = ((v0 & KK) == 0);
        bool s1 = up == ((v0 & JJ) == 0);
        unsigned kq = sop(k0, o, s1);
        unsigned kp = sop(a, c, s1);
        k0 = sop(kq, kp, up == ((v0 & J2) == 0));
      }
      {
        unsigned o = ksh[pb][v1 ^ JJ];
        unsigned a = ksh[pb][v1 ^ J2];
        unsigned c = ksh[pb][v1 ^ (JJ | J2)];
        bool up = ((v1 & KK) == 0);
        bool s1 = up == ((v1 & JJ) == 0);
        unsigned kq = sop(k1, o, s1);
        unsigned kp = sop(a, c, s1);
        k1 = sop(kq, kp, up == ((v1 & J2) == 0));
      }
      pb ^= 1;
    };
    auto tailw = [&](int KK) {              // jj = 32..1
#pragma unroll
      for (int jj = 32; jj > 0; jj >>= 1) shflst(KK, jj);
    };

#pragma unroll
    for (int kk = 2; kk <= 64; kk <<= 1)
#pragma unroll
      for (int jj = kk >> 1; jj > 0; jj >>= 1) shflst(kk, jj);

    local64(128);                       tailw(128);
    lds1(256, 128);   local64(256);     tailw(256);
    lds2(512, 256);   local64(512);     tailw(512);
    lds2(1024, 512);  lds1(1024, 128);  local64(1024);  tailw(1024);

    // bias (x=1.0, idx=IN) rank: elements split across k0/k1 -> two counts
    int r = __syncthreads_count((k0 <= BIASKEY) ? 1 : 0)
          + __syncthreads_count((k1 <= BIASKEY) ? 1 : 0);

    int idx0 = (int)(k0 & 1023u);
    int idx1 = (int)(k1 & 1023u);
    float xs0 = vsh[idx0];
    float xs1 = vsh[idx1];
    int p0 = v0 + (v0 >= r);
    int p1 = v1 + (v1 >= r);
    Pair pr0; pr0.off = (unsigned)(idx0 * OUTS * 4); pr0.x = __float_as_uint(xs0);
    Pair pr1; pr1.off = (unsigned)(idx1 * OUTS * 4); pr1.x = __float_as_uint(xs1);
    ps[p0] = pr0;
    ps[p1] = pr1;
    if (tid == 0) {
      Pair bias; bias.off = (unsigned)(IN * OUTS * 4); bias.x = __float_as_uint(1.0f);
      ps[r] = bias;
      Pair sent; sent.off = 0u; sent.x = __float_as_uint(MAXT);
      ps[N] = sent;
    }
    __syncthreads();
  }

  // ---- Phase B ----
  const char* wbase = (const char*)weight;
  const int is = seg * SEGL;

  // Pass 1 (segs 0..6; seg 7's total feeds no exclusive prefix): 128 rows x
  // 64 cols. quad q = lane&15 -> cols 4q..4q+3 (float4); slice sl = lane>>4
  // takes rows 4uu+sl; combine slices via shfl_xor(16),(32).
  if (seg < NSEG - 1) {
    const int sl = lane >> 4;
    const int q  = lane & 15;
    const unsigned jadd4 = (unsigned)((jc * JCH + q * 4) * 4);
    float4 sw = make_float4(0.f, 0.f, 0.f, 0.f);
    float4 sx = make_float4(0.f, 0.f, 0.f, 0.f);
#pragma unroll 8
    for (int uu = 0; uu < 32; ++uu) {
      Pair p = ps[is + 4 * uu + sl];
      float4 w = *(const float4*)(wbase + (p.off + jadd4));
      float xv = __uint_as_float(p.x);
      sw.x += w.x; sw.y += w.y; sw.z += w.z; sw.w += w.w;
      sx.x = fmaf(w.x, xv, sx.x);
      sx.y = fmaf(w.y, xv, sx.y);
      sx.z = fmaf(w.z, xv, sx.z);
      sx.w = fmaf(w.w, xv, sx.w);
    }
#pragma unroll
    for (int d = 16; d <= 32; d <<= 1) {
      sw.x += __shfl_xor(sw.x, d, 64);  sw.y += __shfl_xor(sw.y, d, 64);
      sw.z += __shfl_xor(sw.z, d, 64);  sw.w += __shfl_xor(sw.w, d, 64);
      sx.x += __shfl_xor(sx.x, d, 64);  sx.y += __shfl_xor(sx.y, d, 64);
      sx.z += __shfl_xor(sx.z, d, 64);  sx.w += __shfl_xor(sx.w, d, 64);
    }
    if (sl == 0) {
      red2[seg][4 * q + 0] = make_float2(sw.x, sx.x);
      red2[seg][4 * q + 1] = make_float2(sw.y, sx.y);
      red2[seg][4 * q + 2] = make_float2(sw.z, sx.z);
      red2[seg][4 * q + 3] = make_float2(sw.w, sx.w);
    }
  }
  __syncthreads();

  // T14-lite: issue pass-2's first Pair2 + both weight loads, then do the
  // prefix math under their latency.
  Pair2 t0 = *(const Pair2*)(ps + is);
  float wa = *(const float*)(wbase + (t0.a.off + jadd));
  float wb = *(const float*)(wbase + (t0.b.off + jadd));

  // Exclusive prefix over segments; wc holds w_cum - 1.
  float wc = -1.0f, wi = 0.0f;
  for (int s = 0; s < seg; ++s) {
    float2 t = red2[s][lane];
    wc += t.x; wi += t.y;
  }

  // Pass 2: 1 col/thread. valid(u) <=> min(wc, -h_prev, h, -bd) >= 0 with
  // h = x_{u+1}*wc - wi (identity g_{u+1} == -h_u exactly); xs sorted =>
  // first valid IS the filtered min (R8 algebra).
  float bn = MAXT, bd = -1.0f;
  float xa = __uint_as_float(t0.a.x);
  float xb = __uint_as_float(t0.b.x);
  float hp = fmaf(xa, wc, -wi);

#pragma unroll 4
  for (int u = 0; u < SEGL; u += 2) {
    Pair2 nx = *(const Pair2*)(ps + is + u + 2);   // ds_read_b128, 16-aligned
    float wn1 = *(const float*)(wbase + (nx.a.off + jadd));  // prefetch
    {  // row u: w=wa, xi=xa, xn=xb
      wc += wa; wi = fmaf(wa, xa, wi);
      float h  = fmaf(xb, wc, -wi);
      float qq = fminf(fminf(wc, -hp), fminf(h, -bd));
      bool f = qq >= 0.0f;
      bn = f ? wi : bn;  bd = f ? wc : bd;  hp = h;
    }
    float wn2 = *(const float*)(wbase + (nx.b.off + jadd));  // prefetch
    float xc = __uint_as_float(nx.a.x);
    {  // row u+1: w=wb, xi=xb, xn=xc
      wc += wb; wi = fmaf(wb, xb, wi);
      float h  = fmaf(xc, wc, -wi);
      float qq = fminf(fminf(wc, -hp), fminf(h, -bd));
      bool f = qq >= 0.0f;
      bn = f ? wi : bn;  bd = f ? wc : bd;  hp = h;
    }
    xa = xc; xb = __uint_as_float(nx.b.x); wa = wn1; wb = wn2;
  }
  if (seg == NSEG - 1) {   // global tail rank 1024; xb = MAXT sentinel
    wc += wa; wi = fmaf(wa, xa, wi);
    float h  = fmaf(xb, wc, -wi);
    float qq = fminf(fminf(wc, -hp), fminf(h, -bd));
    bool f = qq >= 0.0f;
    bn = f ? wi : bn;  bd = f ? wc : bd;
  }
  float best = (bd < 0.0f) ? MAXT : bn * __builtin_amdgcn_rcpf(fmaxf(bd, 1e-10f));

  // Candidates are nonneg floats <= MAXT -> int-bit atomicMin == float min.
  atomicMin(&redm[lane], __float_as_int(best));
  __syncthreads();
  if (tid < JCH / 4) {
    int4 mv = *(const int4*)(&redm[tid * 4]);
    float4 o = make_float4(__int_as_float(mv.x), __int_as_float(mv.y),
                           __int_as_float(mv.z), __int_as_float(mv.w));
    *(float4*)(&out[b * OUTS + jc * JCH + tid * 4]) = o;
  }
}

extern "C" void kernel_launch(void* const* d_in, const int* in_sizes, int n_in,
                              void* d_out, int out_size, void* d_ws, size_t ws_size,
                              hipStream_t stream) {
  const float* layer_in = (const float*)d_in[0];
  const float* weight   = (const float*)d_in[1];
  const float* delay    = (const float*)d_in[2];
  float* out = (float*)d_out;
  (void)d_ws; (void)ws_size;

  snn_fused<<<dim3(B, OUTS / JCH), dim3(64, NSEG), 0, stream>>>(
      layer_in, weight, delay, out);
}